// Round 5
// baseline (876.524 us; speedup 1.0000x reference)
//
#include <hip/hip_runtime.h>
#include <cstdint>

// ---------------------------------------------------------------------------
// ChartParser: span scores + per-batch CKY DP + backtrack.
// B=64, S=256, D=H=1024. Output: int32 [2][B][S] (lefts then rights).
// Round 13 (GEMM1 only; cky/GEMM2/gemmnt unchanged from round 12):
//  - X pre-split once into fp16 limb planes (splitx_kernel, float4-vectorized,
//    stored in the tmpA workspace region which is dead until GEMM2).
//  - gemm_sp_kernel (GEMM1): A AND B staged via global_load_lds width=16 with
//    pre-swizzled global sources; both double-buffered (LDS 64KB, 2 blk/CU);
//    ONE barrier per K-step (m97 structure): DMA k+1 at top of step k,
//    compute k, single vmcnt(0)+lgkmcnt(0) barrier. No in-kernel A split.
//    Numerically bit-identical (same limbs, same products, same order).
// ---------------------------------------------------------------------------

#define Bb 64
#define Ss 256
#define Dd 1024
#define Hh 1024

typedef __attribute__((ext_vector_type(8))) _Float16 f16x8;
typedef __attribute__((ext_vector_type(4))) float f32x4;

// x = h + l + delta, |delta| <= 2^-22 |x| (fp16 RNE twice)
__device__ __forceinline__ void split2(float x, unsigned short& h,
                                       unsigned short& l) {
  _Float16 hh = (_Float16)x;
  _Float16 ll = (_Float16)(x - (float)hh);
  h = __builtin_bit_cast(unsigned short, hh);
  l = __builtin_bit_cast(unsigned short, ll);
}

// async global->LDS, 16B per lane; LDS dest = uniform base + lane*16
__device__ __forceinline__ void gl_lds16(const void* g, void* l) {
  __builtin_amdgcn_global_load_lds(
      (const __attribute__((address_space(1))) void*)g,
      (__attribute__((address_space(3))) void*)l, 16, 0, 0);
}

// ---------------------------------------------------------------------------
// Weight split+transpose: W fp32 [1024 k-rows, ld ldw] -> O fp16 [n][k],
// limb planes at +0, +plane.
// ---------------------------------------------------------------------------
__global__ __launch_bounds__(256) void splitw_kernel(
    const float* __restrict__ W, int ldw, unsigned short* __restrict__ O,
    long long plane) {
  int idx = blockIdx.x * 256 + threadIdx.x;  // n*1024 + k
  int n = idx >> 10, k = idx & 1023;
  float x = W[(long long)k * ldw + n];
  unsigned short h, l;
  split2(x, h, l);
  O[idx] = h;
  O[plane + idx] = l;
}

// X split, no transpose: X fp32 [16M] -> O fp16 planes [16M] h, l.
// float4-vectorized (4 elems/thread).
__global__ __launch_bounds__(256) void splitx_kernel(
    const float* __restrict__ X, unsigned short* __restrict__ O,
    long long plane) {
  long long i4 = ((long long)blockIdx.x * 256 + threadIdx.x) * 4;
  float4 v = *(const float4*)(X + i4);
  unsigned short h[4], l[4];
  split2(v.x, h[0], l[0]);
  split2(v.y, h[1], l[1]);
  split2(v.z, h[2], l[2]);
  split2(v.w, h[3], l[3]);
  uint2 hp, lp;
  hp.x = (unsigned)h[0] | ((unsigned)h[1] << 16);
  hp.y = (unsigned)h[2] | ((unsigned)h[3] << 16);
  lp.x = (unsigned)l[0] | ((unsigned)l[1] << 16);
  lp.y = (unsigned)l[2] | ((unsigned)l[3] << 16);
  *(uint2*)(O + i4) = hp;
  *(uint2*)(O + plane + i4) = lp;
}

// Extract Wbil's bias row / col / corner.
__global__ __launch_bounds__(256) void bilvec_kernel(
    const float* __restrict__ Wbil, float* __restrict__ brow,
    float* __restrict__ bcol, float* __restrict__ corner) {
  int i = blockIdx.x * 256 + threadIdx.x;  // 0..1023
  brow[i] = Wbil[1024 * 1025 + i];
  bcol[i] = Wbil[i * 1025 + 1024];
  if (i == 0) corner[0] = Wbil[1024 * 1025 + 1024];
}

__device__ __forceinline__ void pack8(char* dst, const unsigned short* v) {
  uint4 u;
  u.x = (unsigned)v[0] | ((unsigned)v[1] << 16);
  u.y = (unsigned)v[2] | ((unsigned)v[3] << 16);
  u.z = (unsigned)v[4] | ((unsigned)v[5] << 16);
  u.w = (unsigned)v[6] | ((unsigned)v[7] << 16);
  *(uint4*)dst = u;
}

// split 16 fp32 -> 2x16 fp16 limbs, store (swizzled) to 2 LDS planes
__device__ __forceinline__ void split_store16f(const float* xs, char* lds,
                                               int base, int wa0, int wa1) {
  unsigned short hs[16], ls[16];
#pragma unroll
  for (int i = 0; i < 16; ++i) split2(xs[i], hs[i], ls[i]);
  pack8(&lds[base + wa0], hs);
  pack8(&lds[base + wa1], hs + 8);
  pack8(&lds[base + 8192 + wa0], ls);
  pack8(&lds[base + 8192 + wa1], ls + 8);
}

// 4-product accumulate for one nf column: (ah+al)x(bh+bl), all kept
#define MFMA4(afv, bh, blv, accs, nf)                                        \
  {                                                                          \
    _Pragma("unroll") for (int mf = 0; mf < 4; ++mf) accs[mf][nf] =          \
        __builtin_amdgcn_mfma_f32_16x16x32_f16(afv[0][mf], bh,               \
                                               accs[mf][nf], 0, 0, 0);       \
    _Pragma("unroll") for (int mf = 0; mf < 4; ++mf) accs[mf][nf] =          \
        __builtin_amdgcn_mfma_f32_16x16x32_f16(afv[0][mf], blv,              \
                                               accs[mf][nf], 0, 0, 0);       \
    _Pragma("unroll") for (int mf = 0; mf < 4; ++mf) accs[mf][nf] =          \
        __builtin_amdgcn_mfma_f32_16x16x32_f16(afv[1][mf], bh,               \
                                               accs[mf][nf], 0, 0, 0);       \
    _Pragma("unroll") for (int mf = 0; mf < 4; ++mf) accs[mf][nf] =          \
        __builtin_amdgcn_mfma_f32_16x16x32_f16(afv[1][mf], blv,              \
                                               accs[mf][nf], 0, 0, 0);       \
  }

// ---------------------------------------------------------------------------
// GEMM1 (NN, both operands pre-split fp16): out = act(Asp * Bsp + bias).
// Asp [row][k] limb planes stride aplane; Bsp [n][k] stride bplane.
// Tile 128x128, BK=32, 256 threads, wave-tile 64x64.
// LDS 64KB: Abuf0@0, Abuf1@16384, Bbuf0@32768, Bbuf1@49152 (each buf:
// h 8KB + l 8KB). 16B-chunk XOR swizzle phi(r)=((r>>1)^(r>>3))&3 folded
// into per-lane GLOBAL source (LDS dest linear). ONE barrier per K-step.
// If n0 >= 1024 the block writes C1/bias1 at col-1024 (fused dual output).
// ---------------------------------------------------------------------------
template <bool LEAKY>
__global__ __launch_bounds__(256, 2) void gemm_sp_kernel(
    const unsigned short* __restrict__ Asp, long long aplane,
    const unsigned short* __restrict__ Bsp, long long bplane,
    float* __restrict__ C0, float* __restrict__ C1,
    const float* __restrict__ bias0, const float* __restrict__ bias1) {
  const int m0 = blockIdx.y * 128;
  const int n0 = blockIdx.x * 128;
  __shared__ __align__(16) char lds[65536];
  const int t = threadIdx.x;
  const int L = t & 63, w = t >> 6, q = L >> 4, l15 = L & 15;

  int offA0[4], offB0[4];
#pragma unroll
  for (int f = 0; f < 4; ++f) {
    int rowa = ((w & 1) << 6) + (f << 4) + l15;
    offA0[f] = rowa * 64 + ((q ^ (((rowa >> 1) ^ (rowa >> 3)) & 3)) << 4);
    int rowb = ((w >> 1) << 6) + (f << 4) + l15;
    offB0[f] = rowb * 64 + ((q ^ (((rowb >> 1) ^ (rowb >> 3)) & 3)) << 4);
  }

  // DMA setup: wave w issues 4 x 1KB per operand; lane covers
  // (row = base + lane/4, chunk c = lane&3); source k-chunk = c ^ phi(row).
  const int lrow = L >> 2, lchk = L & 3;
  const unsigned short* asrc[4];
  const unsigned short* bsrc[4];
  int ldso[4];
#pragma unroll
  for (int i = 0; i < 4; ++i) {
    int O = ((w << 2) + i) << 10;  // 0..15360, within a 16KB buf
    int s2 = O >> 13;              // limb plane
    int r = ((O & 8191) >> 6) + lrow;
    int phi = ((r >> 1) ^ (r >> 3)) & 3;
    asrc[i] = Asp + (long long)s2 * aplane + (long long)(m0 + r) * 1024 +
              ((lchk ^ phi) << 3);
    bsrc[i] = Bsp + (long long)s2 * bplane + (long long)(n0 + r) * 1024 +
              ((lchk ^ phi) << 3);
    ldso[i] = O;
  }

  f32x4 acc[4][4];
#pragma unroll
  for (int i = 0; i < 4; ++i)
#pragma unroll
    for (int j = 0; j < 4; ++j) acc[i][j] = (f32x4){0.f, 0.f, 0.f, 0.f};

  // prologue: DMA k0=0 into buf0
#pragma unroll
  for (int i = 0; i < 4; ++i) gl_lds16(asrc[i], &lds[ldso[i]]);
#pragma unroll
  for (int i = 0; i < 4; ++i) gl_lds16(bsrc[i], &lds[32768 + ldso[i]]);
  asm volatile("s_waitcnt vmcnt(0)\n\ts_barrier" ::: "memory");

  int cur = 0;
  for (int k0 = 0; k0 < 1024; k0 += 32) {
    // issue next step's DMA first (lands by this step's end barrier)
    if (k0 < 992) {
      const int an = (cur ^ 1) << 14;
#pragma unroll
      for (int i = 0; i < 4; ++i)
        gl_lds16(asrc[i] + k0 + 32, &lds[an + ldso[i]]);
#pragma unroll
      for (int i = 0; i < 4; ++i)
        gl_lds16(bsrc[i] + k0 + 32, &lds[32768 + an + ldso[i]]);
    }
    const int ab = cur << 14;
    const int bbase = 32768 + ab;
    f16x8 af[2][4];
#pragma unroll
    for (int s = 0; s < 2; ++s)
#pragma unroll
      for (int f = 0; f < 4; ++f)
        af[s][f] = *(const f16x8*)&lds[ab + s * 8192 + offA0[f]];
#pragma unroll
    for (int nf = 0; nf < 4; ++nf) {
      f16x8 bh = *(const f16x8*)&lds[bbase + offB0[nf]];
      f16x8 bl = *(const f16x8*)&lds[bbase + 8192 + offB0[nf]];
      MFMA4(af, bh, bl, acc, nf);
    }
    // single barrier: next-step DMA landed + this step's reads done
    asm volatile("s_waitcnt vmcnt(0) lgkmcnt(0)\n\ts_barrier" ::: "memory");
    cur ^= 1;
  }

  const bool isR = (n0 >= 1024);
  float* Co = isR ? C1 : C0;
  const float* bp = isR ? bias1 : bias0;
  const int nc0 = n0 & 1023;
#pragma unroll
  for (int nf = 0; nf < 4; ++nf) {
    int col = nc0 + ((w >> 1) << 6) + (nf << 4) + l15;
    float bz = bp[col];
#pragma unroll
    for (int mf = 0; mf < 4; ++mf) {
#pragma unroll
      for (int r = 0; r < 4; ++r) {
        int row = m0 + ((w & 1) << 6) + (mf << 4) + (q << 2) + r;
        float x = acc[mf][nf][r] + bz;
        if (LEAKY) x = (x > 0.f) ? x : 0.1f * x;
        Co[(long long)row * 1024 + col] = x;
      }
    }
  }
}

// ---------------------------------------------------------------------------
// MFMA GEMM (NN): out = act(A[M,1024]_fp32 * Bsp + bias). Round-12 version
// (used for GEMM2): B via DMA dbuf, A split in-kernel, 2 barriers/step.
// ---------------------------------------------------------------------------
template <bool LEAKY>
__global__ __launch_bounds__(256, 3) void gemm_mfma_kernel(
    const float* __restrict__ A, const unsigned short* __restrict__ Bsp,
    long long bplane, float* __restrict__ C0, float* __restrict__ C1,
    const float* __restrict__ bias0, const float* __restrict__ bias1) {
  const int m0 = blockIdx.y * 128;
  const int n0 = blockIdx.x * 128;
  __shared__ __align__(16) char lds[49152];
  const int t = threadIdx.x;
  const int L = t & 63, w = t >> 6, q = L >> 4, l15 = L & 15;

  const int ar = t >> 1, ah = t & 1;
  const float* aptr = A + (long long)(m0 + ar) * 1024 + ah * 16;
  const int phiA = ((ar >> 1) ^ (ar >> 3)) & 3;
  const int wa0 = ar * 64 + (((2 * ah + 0) ^ phiA) << 4);
  const int wa1 = ar * 64 + (((2 * ah + 1) ^ phiA) << 4);

  int offA0[4], offB0[4];
#pragma unroll
  for (int f = 0; f < 4; ++f) {
    int rowa = ((w & 1) << 6) + (f << 4) + l15;
    offA0[f] = rowa * 64 + ((q ^ (((rowa >> 1) ^ (rowa >> 3)) & 3)) << 4);
    int rowb = ((w >> 1) << 6) + (f << 4) + l15;
    offB0[f] = rowb * 64 + ((q ^ (((rowb >> 1) ^ (rowb >> 3)) & 3)) << 4);
  }

  const int lrow = L >> 2, lchk = L & 3;
  const unsigned short* bsrc[4];
  int bldso[4];
#pragma unroll
  for (int i = 0; i < 4; ++i) {
    int O = ((w << 2) + i) << 10;
    int s2 = O >> 13;
    int r = ((O & 8191) >> 6) + lrow;
    int phi = ((r >> 1) ^ (r >> 3)) & 3;
    bsrc[i] = Bsp + (long long)s2 * bplane + (long long)(n0 + r) * 1024 +
              ((lchk ^ phi) << 3);
    bldso[i] = O;
  }

  f32x4 acc[4][4];
#pragma unroll
  for (int i = 0; i < 4; ++i)
#pragma unroll
    for (int j = 0; j < 4; ++j) acc[i][j] = (f32x4){0.f, 0.f, 0.f, 0.f};

#pragma unroll
  for (int i = 0; i < 4; ++i) gl_lds16(bsrc[i], &lds[16384 + bldso[i]]);
  float4 a0 = *(const float4*)(aptr + 0);
  float4 a1 = *(const float4*)(aptr + 4);
  float4 a2 = *(const float4*)(aptr + 8);
  float4 a3 = *(const float4*)(aptr + 12);

  int cur = 0;
  for (int k0 = 0; k0 < 1024; k0 += 32) {
    {
      float xs[16] = {a0.x, a0.y, a0.z, a0.w, a1.x, a1.y, a1.z, a1.w,
                      a2.x, a2.y, a2.z, a2.w, a3.x, a3.y, a3.z, a3.w};
      split_store16f(xs, lds, 0, wa0, wa1);
    }
    asm volatile("s_waitcnt vmcnt(0) lgkmcnt(0)\n\ts_barrier" ::: "memory");
    if (k0 < 992) {
      a0 = *(const float4*)(aptr + k0 + 32);
      a1 = *(const float4*)(aptr + k0 + 36);
      a2 = *(const float4*)(aptr + k0 + 40);
      a3 = *(const float4*)(aptr + k0 + 44);
      const int bn = 16384 + ((cur ^ 1) << 14);
#pragma unroll
      for (int i = 0; i < 4; ++i)
        gl_lds16(bsrc[i] + k0 + 32, &lds[bn + bldso[i]]);
    }
    const int bb = 16384 + (cur << 14);
    f16x8 af[2][4];
#pragma unroll
    for (int s = 0; s < 2; ++s)
#pragma unroll
      for (int f = 0; f < 4; ++f)
        af[s][f] = *(const f16x8*)&lds[s * 8192 + offA0[f]];
#pragma unroll
    for (int nf = 0; nf < 4; ++nf) {
      f16x8 bh = *(const f16x8*)&lds[bb + offB0[nf]];
      f16x8 bl = *(const f16x8*)&lds[bb + 8192 + offB0[nf]];
      MFMA4(af, bh, bl, acc, nf);
    }
    asm volatile("s_waitcnt lgkmcnt(0)\n\ts_barrier" ::: "memory");
    cur ^= 1;
  }

  const bool isR = (n0 >= 1024);
  float* Co = isR ? C1 : C0;
  const float* bp = isR ? bias1 : bias0;
  const int nc0 = n0 & 1023;
#pragma unroll
  for (int nf = 0; nf < 4; ++nf) {
    int col = nc0 + ((w >> 1) << 6) + (nf << 4) + l15;
    float bz = bp[col];
#pragma unroll
    for (int mf = 0; mf < 4; ++mf) {
#pragma unroll
      for (int r = 0; r < 4; ++r) {
        int row = m0 + ((w & 1) << 6) + (mf << 4) + (q << 2) + r;
        float x = acc[mf][nf][r] + bz;
        if (LEAKY) x = (x > 0.f) ? x : 0.1f * x;
        Co[(long long)row * 1024 + col] = x;
      }
    }
  }
}

// ---------------------------------------------------------------------------
// Batched NT GEMM on MFMA: C[b] = tmpA[b] * rights[b]^T + rowAdd + scal.
// Both operands fp32, split in-kernel to fp16x2. Tile 128x128, grid (2,2,64).
// ---------------------------------------------------------------------------
__global__ __launch_bounds__(256, 3) void gemmnt_mfma_kernel(
    const float* __restrict__ A, const float* __restrict__ B,
    float* __restrict__ C, const float* __restrict__ rowAdd,
    const float* __restrict__ scal) {
  const int bz = blockIdx.z;
  A += (long long)bz * 256 * 1024;
  B += (long long)bz * 256 * 1024;
  C += (long long)bz * 256 * 256;
  const int m0 = blockIdx.y * 128;
  const int n0 = blockIdx.x * 128;
  __shared__ __align__(16) char lds[32768];
  const int t = threadIdx.x;
  const int L = t & 63, w = t >> 6, q = L >> 4, l15 = L & 15;

  const int ar = t >> 1, ah = t & 1;
  const float* aptr = A + (long long)(m0 + ar) * 1024 + ah * 16;
  const float* bptr = B + (long long)(n0 + ar) * 1024 + ah * 16;
  const int phiA = ((ar >> 1) ^ (ar >> 3)) & 3;
  const int wa0 = ar * 64 + (((2 * ah + 0) ^ phiA) << 4);
  const int wa1 = ar * 64 + (((2 * ah + 1) ^ phiA) << 4);

  int offA0[4], offB0[4];
#pragma unroll
  for (int f = 0; f < 4; ++f) {
    int rowa = ((w & 1) << 6) + (f << 4) + l15;
    offA0[f] = rowa * 64 + ((q ^ (((rowa >> 1) ^ (rowa >> 3)) & 3)) << 4);
    int rowb = ((w >> 1) << 6) + (f << 4) + l15;
    offB0[f] =
        16384 + rowb * 64 + ((q ^ (((rowb >> 1) ^ (rowb >> 3)) & 3)) << 4);
  }

  f32x4 acc[4][4];
#pragma unroll
  for (int i = 0; i < 4; ++i)
#pragma unroll
    for (int j = 0; j < 4; ++j) acc[i][j] = (f32x4){0.f, 0.f, 0.f, 0.f};

  float4 a0 = *(const float4*)(aptr + 0);
  float4 a1 = *(const float4*)(aptr + 4);
  float4 a2 = *(const float4*)(aptr + 8);
  float4 a3 = *(const float4*)(aptr + 12);
  float4 b0 = *(const float4*)(bptr + 0);
  float4 b1 = *(const float4*)(bptr + 4);
  float4 b2 = *(const float4*)(bptr + 8);
  float4 b3 = *(const float4*)(bptr + 12);

  for (int k0 = 0; k0 < 1024; k0 += 32) {
    {
      float xs[16] = {a0.x, a0.y, a0.z, a0.w, a1.x, a1.y, a1.z, a1.w,
                      a2.x, a2.y, a2.z, a2.w, a3.x, a3.y, a3.z, a3.w};
      split_store16f(xs, lds, 0, wa0, wa1);
      float ys[16] = {b0.x, b0.y, b0.z, b0.w, b1.x, b1.y, b1.z, b1.w,
                      b2.x, b2.y, b2.z, b2.w, b3.x, b3.y, b3.z, b3.w};
      split_store16f(ys, lds, 16384, wa0, wa1);
    }
    asm volatile("s_waitcnt lgkmcnt(0)\n\ts_barrier" ::: "memory");
    if (k0 < 992) {
      a0 = *(const float4*)(aptr + k0 + 32);
      a1 = *(const float4*)(aptr + k0 + 36);
      a2 = *(const float4*)(aptr + k0 + 40);
      a3 = *(const float4*)(aptr + k0 + 44);
      b0 = *(const float4*)(bptr + k0 + 32);
      b1 = *(const float4*)(bptr + k0 + 36);
      b2 = *(const float4*)(bptr + k0 + 40);
      b3 = *(const float4*)(bptr + k0 + 44);
    }
    f16x8 af[2][4];
#pragma unroll
    for (int s = 0; s < 2; ++s)
#pragma unroll
      for (int f = 0; f < 4; ++f)
        af[s][f] = *(const f16x8*)&lds[s * 8192 + offA0[f]];
#pragma unroll
    for (int nf = 0; nf < 4; ++nf) {
      f16x8 bh = *(const f16x8*)&lds[offB0[nf]];
      f16x8 bl = *(const f16x8*)&lds[8192 + offB0[nf]];
      MFMA4(af, bh, bl, acc, nf);
    }
    asm volatile("s_waitcnt lgkmcnt(0)\n\ts_barrier" ::: "memory");
  }

  const float sc_add = scal[0];
#pragma unroll
  for (int mf = 0; mf < 4; ++mf) {
#pragma unroll
    for (int r = 0; r < 4; ++r) {
      int row = m0 + ((w & 1) << 6) + (mf << 4) + (q << 2) + r;
      float radd = sc_add + rowAdd[(long long)bz * 256 + row];
#pragma unroll
      for (int nf = 0; nf < 4; ++nf) {
        int col = n0 + ((w >> 1) << 6) + (nf << 4) + l15;
        C[(long long)row * 256 + col] = acc[mf][nf][r] + radd;
      }
    }
  }
}

// ---------------------------------------------------------------------------
// tmpb[i] = dot(lefts[i,:], Wbil[0:H, H]) + Wbil[H,H].  One wave per row.
// ---------------------------------------------------------------------------
__global__ __launch_bounds__(64) void colvec_kernel(
    const float* __restrict__ lefts, const float* __restrict__ bcol,
    const float* __restrict__ corner, float* __restrict__ tmpb) {
  int row = blockIdx.x;
  int lane = threadIdx.x;
  const float* a = lefts + (long long)row * Hh;
  float s = 0.f;
#pragma unroll
  for (int h = lane; h < Hh; h += 64) s = fmaf(a[h], bcol[h], s);
#pragma unroll
  for (int off = 32; off > 0; off >>= 1) s += __shfl_down(s, off, 64);
  if (lane == 0) tmpb[row] = s + corner[0];
}

// ---------------------------------------------------------------------------
// CKY + backtrack. One block per batch, 1024 threads. Chart in LDS, packed
// triangular diag-major. FOUR diagonals per barrier (round 11, unchanged).
// ---------------------------------------------------------------------------
__global__ __launch_bounds__(1024) void cky_kernel(
    const float* __restrict__ scores,  // [64][256][256]
    uint8_t* __restrict__ Sws,         // [64][32896] packed triangular
    int* __restrict__ out)             // [2][64][256] int32
{
  const int b = blockIdx.x;
  const int t = threadIdx.x;
  const int n = Ss;
  const float* sc = scores + (long long)b * n * n;
  uint8_t* SP = Sws + (long long)b * 32896;

  __shared__ float Dch[32896];
  __shared__ float pv[2][2048];
  __shared__ uint8_t pmv[2][2048];
  __shared__ int stk[256];

  // offsets of tiny diags 0..9 (compile-time constants)
  const int offT[10] = {0,    256,  511,  765,  1018,
                        1270, 1521, 1771, 2020, 2268};

  if (t < n) {
    out[b * n + t] = 0;
    out[Bb * n + b * n + t] = 0;
    Dch[t] = 0.f;  // diag 0
  }

  // prologue score prefetch (diags 1..9 at cell t, clamped addresses)
  float PS[10];
  PS[0] = 0.f;
#pragma unroll
  for (int w = 1; w <= 9; ++w) {
    int ic = t;
    if (ic > 255 - w) ic = 255 - w;
    PS[w] = sc[ic * 257 + w];
  }
  asm volatile("s_waitcnt lgkmcnt(0)\n\ts_barrier" ::: "memory");

  // prologue: diags 1..9, one barrier each (generic m-scan, ascending,
  // strict > = first-max)
#pragma unroll
  for (int w = 1; w <= 9; ++w) {
    const int nv = n - w;
    if (t < nv) {
      float bb = Dch[offT[w - 1] + t + 1];  // m=0: 0 + right
      int bm = 0;
#pragma unroll
      for (int m = 1; m < 9; ++m) {
        if (m >= w) break;
        float c = Dch[offT[m] + t] + Dch[offT[w - 1 - m] + t + m + 1];
        if (c > bb) { bb = c; bm = m; }
      }
      const int off = w * 256 - ((w * (w - 1)) >> 1);
      Dch[off + t] = PS[w] + bb;
      SP[off + t] = (uint8_t)bm;
    }
    asm volatile("s_waitcnt lgkmcnt(0)\n\ts_barrier" ::: "memory");
  }

  // generic (b): group partials for superstep with base W0b+4 (4 diags).
  // Covers m in [jb+4, W0b-1] (left/right spans are diags <= W0b-1, i.e.
  // >= 1 barrier old when run inside superstep W0b). Writes pv/pmv[pbuf].
  auto run_b = [&](int W0b, int pbuf) {
    const int cnv = n - W0b - 4;  // cells of consumer's first diag
    int jb, gb, u, delta, lgGHL, SLOTG;
    if (cnv > 128) {  // RA: 2 groups/diag, T=128, slices (u, u+128)
      const int p = t >> 7;
      jb = 3 - (p >> 1);
      gb = 1 - (p & 1);
      u = t & 127;
      delta = 128;
      lgGHL = 1;
      SLOTG = 256;
    } else {  // RB/RC: 4 groups/diag, T=64
      const int wid = t >> 6;
      jb = 3 - (wid >> 2);
      gb = 3 - (wid & 3);
      u = t & 63;
      delta = (cnv > 64) ? 64 : 0;
      lgGHL = 2;
      SLOTG = 128;
    }
    const int Wb = W0b + 4 + jb;
    const int nvb = n - Wb;
    int cnt = W0b - jb - 4;
    if (cnt < 0) cnt = 0;
    const int per = (cnt + (1 << lgGHL) - 1) >> lgGHL;
    const int mlo = jb + 4;
    int ml = mlo + gb * per;
    int mh = mlo + cnt;
    {
      int e = ml + per;
      if (e < mh) mh = e;
    }
    float b0 = -3.0e38f, b1 = -3.0e38f;
    int m0i = ml, m1i = ml;
    if (u < nvb && ml < mh) {
      int al = ml * n - ((ml * (ml - 1)) >> 1) + u;
      const int kr = Wb - 1 - ml;
      int ar = kr * n - ((kr * (kr - 1)) >> 1) + u + ml + 1;
      int dl = n - ml;
      int dr = n - Wb + ml + 1;
      if (delta) {
#pragma unroll 2
        for (int m = ml; m < mh; ++m) {
          float l0 = Dch[al], l1 = Dch[al + delta];  // -> ds_read2_b32
          float r0 = Dch[ar], r1 = Dch[ar + delta];  // -> ds_read2_b32
          float c0 = l0 + r0, c1 = l1 + r1;
          if (c0 > b0) { b0 = c0; m0i = m; }  // strict > = first max
          if (c1 > b1) { b1 = c1; m1i = m; }
          al += dl;
          ar -= dr;
          --dl;
          ++dr;
        }
      } else {
#pragma unroll 4
        for (int m = ml; m < mh; ++m) {
          float c = Dch[al] + Dch[ar];
          if (c > b0) { b0 = c; m0i = m; }
          al += dl;
          ar -= dr;
          --dl;
          ++dr;
        }
      }
    }
    const int slot = jb * 512 + gb * SLOTG + u;
    pv[pbuf][slot] = b0;
    pmv[pbuf][slot] = (uint8_t)m0i;
    if (delta) {
      pv[pbuf][slot + delta] = b1;
      pmv[pbuf][slot + delta] = (uint8_t)m1i;
    }
  };

  // prologue (b): partials for s=3 (diags 10..13), "s=2" role -> pv[0]
  run_b(6, 0);
  asm volatile("s_waitcnt lgkmcnt(0)\n\ts_barrier" ::: "memory");

  // (a)-band geometry: wave wv covers cells 61*wv + lane (3-lane overlap)
  const int wv = t >> 6, lane = t & 63;
  const int tcell = 61 * wv + lane;

  // seed scores for s=3 (diags 10..13)
  float scA[4];
#pragma unroll
  for (int j = 0; j < 4; ++j) {
    const int Wn = 10 + j;
    int ic = tcell;
    if (ic > 255 - Wn) ic = 255 - Wn;
    if (ic < 0) ic = 0;
    scA[j] = sc[ic * 257 + Wn];
  }

  for (int s = 3; s <= 64; ++s) {
    const int W0 = 4 * s - 2;
    const int nv1 = n - W0;
    const int pb = s & 1, po = pb ^ 1;
    const int nb = (nv1 + 60) / 61;

    // prefetch next superstep's scores (diags W0+4..W0+7)
    float P4[4] = {0.f, 0.f, 0.f, 0.f};
    if (s < 64 && wv < nb) {
#pragma unroll
      for (int j = 0; j < 4; ++j) {
        const int Wn = W0 + 4 + j;
        int ic = tcell;
        if (ic > 255 - Wn) ic = 255 - Wn;
        if (ic < 0) ic = 0;
        P4[j] = sc[ic * 257 + Wn];
      }
    }

    // ---- (a): finalize diags W0..W0+3 ----
    if (wv < nb) {
      const int tc = (tcell < nv1) ? tcell : (nv1 - 1);  // clamped (safe)
      const float* pvo = pv[po];
      const uint8_t* pmo = pmv[po];
      int GHa, SGa;
      if (nv1 > 128) { GHa = 2; SGa = 256; } else { GHa = 4; SGa = 128; }
      int offPB[4], offCB[4];
#pragma unroll
      for (int d = 0; d < 4; ++d) {
        const int dg = W0 - 4 + d;
        offPB[d] = dg * 256 - ((dg * (dg - 1)) >> 1);
        const int cg = W0 + d;
        offCB[d] = cg * 256 - ((cg * (cg - 1)) >> 1);
      }
      float VAL0, VAL1, VAL2, VAL3;
      float SH01, SH02, SH03, SH11, SH12, SH21;
      // ---------------- j = 0 (W = W0) ----------------
      {
        const int W = W0;
        float bb = Dch[offPB[3] + tc + 1];  // m=0: 0 + prev-batch diag W-1
        int bm = 0;
#pragma unroll
        for (int dm = 1; dm < 4; ++dm) {  // static-low m = dm
          const int m = dm;
          float c = Dch[offT[m] + tc] + Dch[offPB[3 - dm] + tc + m + 1];
          if (c > bb) { bb = c; bm = m; }
        }
#pragma unroll
        for (int g = 0; g < 4; ++g) {  // partials [4, W0-5]
          if (g >= GHa) break;
          const int sl = g * SGa + tc;
          float x = pvo[sl];
          if (x > bb) { bb = x; bm = pmo[sl]; }
        }
#pragma unroll
        for (int dr = 3; dr >= 0; --dr) {  // static-high m = W0-1-dr asc
          const int r = dr;
          const int m = W - 1 - r;
          float right = (r == 0) ? 0.f : Dch[offT[r] + tc + W - r];
          float c = Dch[offPB[3 - dr] + tc] + right;
          if (c > bb) { bb = c; bm = m; }
        }
        VAL0 = scA[0] + bb;
        if (tcell < nv1) {
          Dch[offCB[0] + tcell] = VAL0;
          SP[offCB[0] + tcell] = (uint8_t)bm;
        }
        SH01 = __shfl_down(VAL0, 1, 64);
        SH02 = __shfl_down(VAL0, 2, 64);
        SH03 = __shfl_down(VAL0, 3, 64);
      }
      // ---------------- j = 1 (W = W0+1) ----------------
      {
        const int W = W0 + 1;
        float bb = SH01;  // m=0: 0 + VAL0(t+1)
        int bm = 0;
#pragma unroll
        for (int dm = 0; dm < 4; ++dm) {  // static-low m = 1+dm
          const int m = 1 + dm;
          float c = Dch[offT[m] + tc] + Dch[offPB[3 - dm] + tc + m + 1];
          if (c > bb) { bb = c; bm = m; }
        }
#pragma unroll
        for (int g = 0; g < 4; ++g) {
          if (g >= GHa) break;
          const int sl = 512 + g * SGa + tc;
          float x = pvo[sl];
          if (x > bb) { bb = x; bm = pmo[sl]; }
        }
#pragma unroll
        for (int dr = 3; dr >= 0; --dr) {  // static-high r = 1+dr
          const int r = 1 + dr;
          const int m = W - 1 - r;  // = W0-1-dr, ascending
          float c = Dch[offPB[3 - dr] + tc] + Dch[offT[r] + tc + W - r];
          if (c > bb) { bb = c; bm = m; }
        }
        // dyn-high r=0: m = W-1: left = VAL0, right = 0
        if (VAL0 > bb) { bb = VAL0; bm = W - 1; }
        VAL1 = scA[1] + bb;
        if (lane <= 62 && tcell < nv1 - 1) {
          Dch[offCB[1] + tcell] = VAL1;
          SP[offCB[1] + tcell] = (uint8_t)bm;
        }
        SH11 = __shfl_down(VAL1, 1, 64);
        SH12 = __shfl_down(VAL1, 2, 64);
      }
      // ---------------- j = 2 (W = W0+2) ----------------
      {
        const int W = W0 + 2;
        float bb = SH11;  // m=0: 0 + VAL1(t+1)
        int bm = 0;
        {  // dyn-low m=1: diag1 + VAL0(t+2)
          float c = Dch[offT[1] + tc] + SH02;
          if (c > bb) { bb = c; bm = 1; }
        }
#pragma unroll
        for (int dm = 0; dm < 4; ++dm) {  // static-low m = 2+dm
          const int m = 2 + dm;
          float c = Dch[offT[m] + tc] + Dch[offPB[3 - dm] + tc + m + 1];
          if (c > bb) { bb = c; bm = m; }
        }
#pragma unroll
        for (int g = 0; g < 4; ++g) {
          if (g >= GHa) break;
          const int sl = 1024 + g * SGa + tc;
          float x = pvo[sl];
          if (x > bb) { bb = x; bm = pmo[sl]; }
        }
#pragma unroll
        for (int dr = 3; dr >= 0; --dr) {  // static-high r = 2+dr
          const int r = 2 + dr;
          const int m = W - 1 - r;  // = W0-1-dr
          float c = Dch[offPB[3 - dr] + tc] + Dch[offT[r] + tc + W - r];
          if (c > bb) { bb = c; bm = m; }
        }
        {  // dyn-high r=1: m = W-2 = W0: VAL0 + diag1(t+W-1)
          float c = VAL0 + Dch[offT[1] + tc + W - 1];
          if (c > bb) { bb = c; bm = W - 2; }
        }
        // dyn-high r=0: m = W-1: VAL1 + 0
        if (VAL1 > bb) { bb = VAL1; bm = W - 1; }
        VAL2 = scA[2] + bb;
        if (lane <= 61 && tcell < nv1 - 2) {
          Dch[offCB[2] + tcell] = VAL2;
          SP[offCB[2] + tcell] = (uint8_t)bm;
        }
        SH21 = __shfl_down(VAL2, 1, 64);
      }
      // ---------------- j = 3 (W = W0+3) ----------------
      {
        const int W = W0 + 3;
        float bb = SH21;  // m=0: 0 + VAL2(t+1)
        int bm = 0;
        {  // dyn-low m=1: diag1 + VAL1(t+2)
          float c = Dch[offT[1] + tc] + SH12;
          if (c > bb) { bb = c; bm = 1; }
        }
        {  // dyn-low m=2: diag2 + VAL0(t+3)
          float c = Dch[offT[2] + tc] + SH03;
          if (c > bb) { bb = c; bm = 2; }
        }
#pragma unroll
        for (int dm = 0; dm < 4; ++dm) {  // static-low m = 3+dm
          const int m = 3 + dm;
          float c = Dch[offT[m] + tc] + Dch[offPB[3 - dm] + tc + m + 1];
          if (c > bb) { bb = c; bm = m; }
        }
#pragma unroll
        for (int g = 0; g < 4; ++g) {
          if (g >= GHa) break;
          const int sl = 1536 + g * SGa + tc;
          float x = pvo[sl];
          if (x > bb) { bb = x; bm = pmo[sl]; }
        }
#pragma unroll
        for (int dr = 3; dr >= 0; --dr) {  // static-high r = 3+dr
          const int r = 3 + dr;
          const int m = W - 1 - r;  // = W0-1-dr
          float c = Dch[offPB[3 - dr] + tc] + Dch[offT[r] + tc + W - r];
          if (c > bb) { bb = c; bm = m; }
        }
        {  // dyn-high r=2: m = W-3 = W0: VAL0 + diag2(t+W-2)
          float c = VAL0 + Dch[offT[2] + tc + W - 2];
          if (c > bb) { bb = c; bm = W - 3; }
        }
        {  // dyn-high r=1: m = W-2 = W0+1: VAL1 + diag1(t+W-1)
          float c = VAL1 + Dch[offT[1] + tc + W - 1];
          if (c > bb) { bb = c; bm = W - 2; }
        }
        // dyn-high r=0: m = W-1: VAL2 + 0
        if (VAL2 > bb) { bb = VAL2; bm = W - 1; }
        VAL3 = scA[3] + bb;
        if (lane <= 60 && tcell < nv1 - 3) {
          Dch[offCB[3] + tcell] = VAL3;
          SP[offCB[3] + tcell] = (uint8_t)bm;
        }
      }
    }

    // ---- (b): partials for superstep s+1 (diags W0+4..W0+7) ----
    if (s < 64) run_b(W0, pb);

    asm volatile("s_waitcnt lgkmcnt(0)\n\ts_barrier" ::: "memory");
#pragma unroll
    for (int j = 0; j < 4; ++j) scA[j] = P4[j];
  }

  // Drain all SP stores (whole loop's worth) once, then barrier.
  asm volatile("s_waitcnt vmcnt(0) lgkmcnt(0)\n\ts_barrier" ::: "memory");
  uint8_t* spl = (uint8_t*)Dch;
  for (int idx = t; idx < 32896; idx += 1024) spl[idx] = SP[idx];
  asm volatile("s_waitcnt vmcnt(0) lgkmcnt(0)\n\ts_barrier" ::: "memory");
  if (t == 0) {
    int top = 0;
    stk[top++] = (0 << 16) | (n - 1);
    int cnt = 0;
    for (int step = 0; step < n - 1; ++step) {
      if (top > 0) {
        int ij = stk[--top];
        int ii = ij >> 16, jj = ij & 0xffff;
        out[b * n + cnt] = ii;
        out[Bb * n + b * n + cnt] = jj;
        ++cnt;
        int k = jj - ii;
        int s2 = ii + (int)spl[k * n - ((k * (k - 1)) >> 1) + ii];
        stk[top] = (ii << 16) | s2;
        if (s2 > ii) ++top;
        stk[top] = ((s2 + 1) << 16) | jj;
        if (jj > s2 + 1) ++top;
      }
    }
  }
}

// ---------------------------------------------------------------------------
// Launch
// ---------------------------------------------------------------------------
extern "C" void kernel_launch(void* const* d_in, const int* in_sizes, int n_in,
                              void* d_out, int out_size, void* d_ws,
                              size_t ws_size, hipStream_t stream) {
  const float* X = (const float*)d_in[0];     // [64,256,1024]
  const float* Wl = (const float*)d_in[2];    // [1024,1024]
  const float* bl = (const float*)d_in[3];    // [1024]
  const float* Wr = (const float*)d_in[4];
  const float* br = (const float*)d_in[5];
  const float* Wbil = (const float*)d_in[6];  // [1025,1025]
  const float* bbil = (const float*)d_in[7];  // scalar
  int* out = (int*)d_out;

  // workspace layout
  float* ws = (float*)d_ws;
  float* lefts = ws;                          // 16777216 f
  float* rights = lefts + 16777216;           // 16777216 f
  float* tmpA = rights + 16777216;            // 16777216 f
  float* scoresP = tmpA + 16777216;           // 4194304 f
  float* tmpb = scoresP + 4194304;            // 16384 f
  float* browp = tmpb + 16384;                // 1024 f
  float* bcolp = browp + 1024;                // 1024 f
  float* cornerp = bcolp + 1024;              // 4 f
  unsigned short* Wlrt = (unsigned short*)(cornerp + 4);  // 2 x 2M fp16
  unsigned short* Wct = Wlrt + 2LL * 2097152;             // 2 x 1M fp16
  uint8_t* SPp = (uint8_t*)(Wct + 2LL * 1048576);         // 64x32896 u8

  // X pre-split limb planes live in the (dead-until-GEMM2) tmpA region:
  // 2 x 16777216 fp16 = 64MB = sizeof(tmpA). GEMM2 overwrites it later.
  unsigned short* Xsp = (unsigned short*)tmpA;

  // weight splits (+ Wbil bias vectors) + X split
  splitw_kernel<<<dim3(4096), 256, 0, stream>>>(Wl, 1024, Wlrt, 2097152);
  splitw_kernel<<<dim3(4096), 256, 0, stream>>>(Wr, 1024, Wlrt + 1048576,
                                                2097152);
  splitw_kernel<<<dim3(4096), 256, 0, stream>>>(Wbil, 1025, Wct, 1048576);
  bilvec_kernel<<<dim3(4), 256, 0, stream>>>(Wbil, browp, bcolp, cornerp);
  splitx_kernel<<<dim3(16384), 256, 0, stream>>>(X, Xsp, 16777216LL);

  // fused lefts|rights GEMM: N=2048, pre-split A and B, 1 barrier/K-step
  dim3 gLR(16, 128);
  gemm_sp_kernel<true><<<gLR, 256, 0, stream>>>(
      Xsp, 16777216LL, Wlrt, 2097152LL, lefts, rights, bl, br);

  colvec_kernel<<<dim3(16384), 64, 0, stream>>>(lefts, bcolp, cornerp, tmpb);

  dim3 gA(8, 128);
  gemm_mfma_kernel<false><<<gA, 256, 0, stream>>>(lefts, Wct, 1048576LL, tmpA,
                                                  tmpA, browp, browp);

  dim3 g3(2, 2, 64);
  gemmnt_mfma_kernel<<<g3, 256, 0, stream>>>(tmpA, rights, scoresP, tmpb,
                                             bbil);

  cky_kernel<<<dim3(Bb), dim3(1024), 0, stream>>>(scoresP, SPp, out);
}

// Round 6
// 863.385 us; speedup vs baseline: 1.0152x; 1.0152x over previous
//
#include <hip/hip_runtime.h>
#include <cstdint>

// ---------------------------------------------------------------------------
// ChartParser: span scores + per-batch CKY DP + backtrack.
// B=64, S=256, D=H=1024. Output: int32 [2][B][S] (lefts then rights).
// Round 14:
//  - GEMM1 reverted to round-12 gemm_mfma (splitx + gemm_sp removed: the
//    2-blk/CU single-barrier variant was neutral and splitx pure overhead).
//  - cky: EIGHT diagonals per barrier. Superstep s (s=2..31, W0=8s)
//    finalizes diags W0..W0+7 in (a) using partials from (b) of s-1
//    (m in [j+8, W0-9], all >= 1-barrier-old spans). Extremes in (a):
//    dyn-low [0,j-1] via __shfl_down (dist <= 7), static-low [j,j+7]
//    (tiny diag x prev-batch), static-high [W0-8,W0-1] (prev-batch x tiny),
//    dyn-high [W0,W-1] (register VALs x tiny). Bands stride 57, 7-lane
//    overlap, write guard lane <= 63-j. Prologue diags 1..15 (generic).
//    At s=2 static-low/high overlap duplicates are bit-identical (same LDS
//    addresses) so strict '>' preserves exact first-max; pv[1] = -inf makes
//    the empty partial range inert. Coverage ascending+contiguous => exact
//    jnp.argmax semantics. LDS unchanged 153088 B.
// ---------------------------------------------------------------------------

#define Bb 64
#define Ss 256
#define Dd 1024
#define Hh 1024

typedef __attribute__((ext_vector_type(8))) _Float16 f16x8;
typedef __attribute__((ext_vector_type(4))) float f32x4;

// x = h + l + delta, |delta| <= 2^-22 |x| (fp16 RNE twice)
__device__ __forceinline__ void split2(float x, unsigned short& h,
                                       unsigned short& l) {
  _Float16 hh = (_Float16)x;
  _Float16 ll = (_Float16)(x - (float)hh);
  h = __builtin_bit_cast(unsigned short, hh);
  l = __builtin_bit_cast(unsigned short, ll);
}

// async global->LDS, 16B per lane; LDS dest = uniform base + lane*16
__device__ __forceinline__ void gl_lds16(const void* g, void* l) {
  __builtin_amdgcn_global_load_lds(
      (const __attribute__((address_space(1))) void*)g,
      (__attribute__((address_space(3))) void*)l, 16, 0, 0);
}

// ---------------------------------------------------------------------------
// Weight split+transpose: W fp32 [1024 k-rows, ld ldw] -> O fp16 [n][k],
// limb planes at +0, +plane.
// ---------------------------------------------------------------------------
__global__ __launch_bounds__(256) void splitw_kernel(
    const float* __restrict__ W, int ldw, unsigned short* __restrict__ O,
    long long plane) {
  int idx = blockIdx.x * 256 + threadIdx.x;  // n*1024 + k
  int n = idx >> 10, k = idx & 1023;
  float x = W[(long long)k * ldw + n];
  unsigned short h, l;
  split2(x, h, l);
  O[idx] = h;
  O[plane + idx] = l;
}

// Extract Wbil's bias row / col / corner.
__global__ __launch_bounds__(256) void bilvec_kernel(
    const float* __restrict__ Wbil, float* __restrict__ brow,
    float* __restrict__ bcol, float* __restrict__ corner) {
  int i = blockIdx.x * 256 + threadIdx.x;  // 0..1023
  brow[i] = Wbil[1024 * 1025 + i];
  bcol[i] = Wbil[i * 1025 + 1024];
  if (i == 0) corner[0] = Wbil[1024 * 1025 + 1024];
}

__device__ __forceinline__ void pack8(char* dst, const unsigned short* v) {
  uint4 u;
  u.x = (unsigned)v[0] | ((unsigned)v[1] << 16);
  u.y = (unsigned)v[2] | ((unsigned)v[3] << 16);
  u.z = (unsigned)v[4] | ((unsigned)v[5] << 16);
  u.w = (unsigned)v[6] | ((unsigned)v[7] << 16);
  *(uint4*)dst = u;
}

// split 16 fp32 -> 2x16 fp16 limbs, store (swizzled) to 2 LDS planes
__device__ __forceinline__ void split_store16f(const float* xs, char* lds,
                                               int base, int wa0, int wa1) {
  unsigned short hs[16], ls[16];
#pragma unroll
  for (int i = 0; i < 16; ++i) split2(xs[i], hs[i], ls[i]);
  pack8(&lds[base + wa0], hs);
  pack8(&lds[base + wa1], hs + 8);
  pack8(&lds[base + 8192 + wa0], ls);
  pack8(&lds[base + 8192 + wa1], ls + 8);
}

// 4-product accumulate for one nf column: (ah+al)x(bh+bl), all kept
#define MFMA4(afv, bh, blv, accs, nf)                                        \
  {                                                                          \
    _Pragma("unroll") for (int mf = 0; mf < 4; ++mf) accs[mf][nf] =          \
        __builtin_amdgcn_mfma_f32_16x16x32_f16(afv[0][mf], bh,               \
                                               accs[mf][nf], 0, 0, 0);       \
    _Pragma("unroll") for (int mf = 0; mf < 4; ++mf) accs[mf][nf] =          \
        __builtin_amdgcn_mfma_f32_16x16x32_f16(afv[0][mf], blv,              \
                                               accs[mf][nf], 0, 0, 0);       \
    _Pragma("unroll") for (int mf = 0; mf < 4; ++mf) accs[mf][nf] =          \
        __builtin_amdgcn_mfma_f32_16x16x32_f16(afv[1][mf], bh,               \
                                               accs[mf][nf], 0, 0, 0);       \
    _Pragma("unroll") for (int mf = 0; mf < 4; ++mf) accs[mf][nf] =          \
        __builtin_amdgcn_mfma_f32_16x16x32_f16(afv[1][mf], blv,              \
                                               accs[mf][nf], 0, 0, 0);       \
  }

// ---------------------------------------------------------------------------
// MFMA GEMM (NN): out = act(A[M,1024]_fp32 * Bsp + bias). Bsp pre-split fp16
// [n][k], limb planes at stride bplane. Tile 128x128, BK=32, 256 threads,
// wave-tile 64x64. LDS 48KB: Ah@0, Al@8192, Bbuf0@16384, Bbuf1@32768.
// B via global_load_lds w=16 (pre-swizzled source), dbuf, issued 1 step
// ahead; A fp32 regs prefetched 1 step ahead, split in-kernel.
// If n0 >= 1024 the block writes C1/bias1 at col-1024 (fused dual output).
// ---------------------------------------------------------------------------
template <bool LEAKY>
__global__ __launch_bounds__(256, 3) void gemm_mfma_kernel(
    const float* __restrict__ A, const unsigned short* __restrict__ Bsp,
    long long bplane, float* __restrict__ C0, float* __restrict__ C1,
    const float* __restrict__ bias0, const float* __restrict__ bias1) {
  const int m0 = blockIdx.y * 128;
  const int n0 = blockIdx.x * 128;
  __shared__ __align__(16) char lds[49152];
  const int t = threadIdx.x;
  const int L = t & 63, w = t >> 6, q = L >> 4, l15 = L & 15;

  const int ar = t >> 1, ah = t & 1;
  const float* aptr = A + (long long)(m0 + ar) * 1024 + ah * 16;
  const int phiA = ((ar >> 1) ^ (ar >> 3)) & 3;
  const int wa0 = ar * 64 + (((2 * ah + 0) ^ phiA) << 4);
  const int wa1 = ar * 64 + (((2 * ah + 1) ^ phiA) << 4);

  int offA0[4], offB0[4];
#pragma unroll
  for (int f = 0; f < 4; ++f) {
    int rowa = ((w & 1) << 6) + (f << 4) + l15;
    offA0[f] = rowa * 64 + ((q ^ (((rowa >> 1) ^ (rowa >> 3)) & 3)) << 4);
    int rowb = ((w >> 1) << 6) + (f << 4) + l15;
    offB0[f] = rowb * 64 + ((q ^ (((rowb >> 1) ^ (rowb >> 3)) & 3)) << 4);
  }

  const int lrow = L >> 2, lchk = L & 3;
  const unsigned short* bsrc[4];
  int bldso[4];
#pragma unroll
  for (int i = 0; i < 4; ++i) {
    int O = ((w << 2) + i) << 10;
    int s2 = O >> 13;
    int r = ((O & 8191) >> 6) + lrow;
    int phi = ((r >> 1) ^ (r >> 3)) & 3;
    bsrc[i] = Bsp + (long long)s2 * bplane + (long long)(n0 + r) * 1024 +
              ((lchk ^ phi) << 3);
    bldso[i] = O;
  }

  f32x4 acc[4][4];
#pragma unroll
  for (int i = 0; i < 4; ++i)
#pragma unroll
    for (int j = 0; j < 4; ++j) acc[i][j] = (f32x4){0.f, 0.f, 0.f, 0.f};

#pragma unroll
  for (int i = 0; i < 4; ++i) gl_lds16(bsrc[i], &lds[16384 + bldso[i]]);
  float4 a0 = *(const float4*)(aptr + 0);
  float4 a1 = *(const float4*)(aptr + 4);
  float4 a2 = *(const float4*)(aptr + 8);
  float4 a3 = *(const float4*)(aptr + 12);

  int cur = 0;
  for (int k0 = 0; k0 < 1024; k0 += 32) {
    {
      float xs[16] = {a0.x, a0.y, a0.z, a0.w, a1.x, a1.y, a1.z, a1.w,
                      a2.x, a2.y, a2.z, a2.w, a3.x, a3.y, a3.z, a3.w};
      split_store16f(xs, lds, 0, wa0, wa1);
    }
    asm volatile("s_waitcnt vmcnt(0) lgkmcnt(0)\n\ts_barrier" ::: "memory");
    if (k0 < 992) {
      a0 = *(const float4*)(aptr + k0 + 32);
      a1 = *(const float4*)(aptr + k0 + 36);
      a2 = *(const float4*)(aptr + k0 + 40);
      a3 = *(const float4*)(aptr + k0 + 44);
      const int bn = 16384 + ((cur ^ 1) << 14);
#pragma unroll
      for (int i = 0; i < 4; ++i)
        gl_lds16(bsrc[i] + k0 + 32, &lds[bn + bldso[i]]);
    }
    const int bb = 16384 + (cur << 14);
    f16x8 af[2][4];
#pragma unroll
    for (int s = 0; s < 2; ++s)
#pragma unroll
      for (int f = 0; f < 4; ++f)
        af[s][f] = *(const f16x8*)&lds[s * 8192 + offA0[f]];
#pragma unroll
    for (int nf = 0; nf < 4; ++nf) {
      f16x8 bh = *(const f16x8*)&lds[bb + offB0[nf]];
      f16x8 bl = *(const f16x8*)&lds[bb + 8192 + offB0[nf]];
      MFMA4(af, bh, bl, acc, nf);
    }
    asm volatile("s_waitcnt lgkmcnt(0)\n\ts_barrier" ::: "memory");
    cur ^= 1;
  }

  const bool isR = (n0 >= 1024);
  float* Co = isR ? C1 : C0;
  const float* bp = isR ? bias1 : bias0;
  const int nc0 = n0 & 1023;
#pragma unroll
  for (int nf = 0; nf < 4; ++nf) {
    int col = nc0 + ((w >> 1) << 6) + (nf << 4) + l15;
    float bz = bp[col];
#pragma unroll
    for (int mf = 0; mf < 4; ++mf) {
#pragma unroll
      for (int r = 0; r < 4; ++r) {
        int row = m0 + ((w & 1) << 6) + (mf << 4) + (q << 2) + r;
        float x = acc[mf][nf][r] + bz;
        if (LEAKY) x = (x > 0.f) ? x : 0.1f * x;
        Co[(long long)row * 1024 + col] = x;
      }
    }
  }
}

// ---------------------------------------------------------------------------
// Batched NT GEMM on MFMA: C[b] = tmpA[b] * rights[b]^T + rowAdd + scal.
// Both operands fp32, split in-kernel to fp16x2. Tile 128x128, grid (2,2,64).
// ---------------------------------------------------------------------------
__global__ __launch_bounds__(256, 3) void gemmnt_mfma_kernel(
    const float* __restrict__ A, const float* __restrict__ B,
    float* __restrict__ C, const float* __restrict__ rowAdd,
    const float* __restrict__ scal) {
  const int bz = blockIdx.z;
  A += (long long)bz * 256 * 1024;
  B += (long long)bz * 256 * 1024;
  C += (long long)bz * 256 * 256;
  const int m0 = blockIdx.y * 128;
  const int n0 = blockIdx.x * 128;
  __shared__ __align__(16) char lds[32768];
  const int t = threadIdx.x;
  const int L = t & 63, w = t >> 6, q = L >> 4, l15 = L & 15;

  const int ar = t >> 1, ah = t & 1;
  const float* aptr = A + (long long)(m0 + ar) * 1024 + ah * 16;
  const float* bptr = B + (long long)(n0 + ar) * 1024 + ah * 16;
  const int phiA = ((ar >> 1) ^ (ar >> 3)) & 3;
  const int wa0 = ar * 64 + (((2 * ah + 0) ^ phiA) << 4);
  const int wa1 = ar * 64 + (((2 * ah + 1) ^ phiA) << 4);

  int offA0[4], offB0[4];
#pragma unroll
  for (int f = 0; f < 4; ++f) {
    int rowa = ((w & 1) << 6) + (f << 4) + l15;
    offA0[f] = rowa * 64 + ((q ^ (((rowa >> 1) ^ (rowa >> 3)) & 3)) << 4);
    int rowb = ((w >> 1) << 6) + (f << 4) + l15;
    offB0[f] =
        16384 + rowb * 64 + ((q ^ (((rowb >> 1) ^ (rowb >> 3)) & 3)) << 4);
  }

  f32x4 acc[4][4];
#pragma unroll
  for (int i = 0; i < 4; ++i)
#pragma unroll
    for (int j = 0; j < 4; ++j) acc[i][j] = (f32x4){0.f, 0.f, 0.f, 0.f};

  float4 a0 = *(const float4*)(aptr + 0);
  float4 a1 = *(const float4*)(aptr + 4);
  float4 a2 = *(const float4*)(aptr + 8);
  float4 a3 = *(const float4*)(aptr + 12);
  float4 b0 = *(const float4*)(bptr + 0);
  float4 b1 = *(const float4*)(bptr + 4);
  float4 b2 = *(const float4*)(bptr + 8);
  float4 b3 = *(const float4*)(bptr + 12);

  for (int k0 = 0; k0 < 1024; k0 += 32) {
    {
      float xs[16] = {a0.x, a0.y, a0.z, a0.w, a1.x, a1.y, a1.z, a1.w,
                      a2.x, a2.y, a2.z, a2.w, a3.x, a3.y, a3.z, a3.w};
      split_store16f(xs, lds, 0, wa0, wa1);
      float ys[16] = {b0.x, b0.y, b0.z, b0.w, b1.x, b1.y, b1.z, b1.w,
                      b2.x, b2.y, b2.z, b2.w, b3.x, b3.y, b3.z, b3.w};
      split_store16f(ys, lds, 16384, wa0, wa1);
    }
    asm volatile("s_waitcnt lgkmcnt(0)\n\ts_barrier" ::: "memory");
    if (k0 < 992) {
      a0 = *(const float4*)(aptr + k0 + 32);
      a1 = *(const float4*)(aptr + k0 + 36);
      a2 = *(const float4*)(aptr + k0 + 40);
      a3 = *(const float4*)(aptr + k0 + 44);
      b0 = *(const float4*)(bptr + k0 + 32);
      b1 = *(const float4*)(bptr + k0 + 36);
      b2 = *(const float4*)(bptr + k0 + 40);
      b3 = *(const float4*)(bptr + k0 + 44);
    }
    f16x8 af[2][4];
#pragma unroll
    for (int s = 0; s < 2; ++s)
#pragma unroll
      for (int f = 0; f < 4; ++f)
        af[s][f] = *(const f16x8*)&lds[s * 8192 + offA0[f]];
#pragma unroll
    for (int nf = 0; nf < 4; ++nf) {
      f16x8 bh = *(const f16x8*)&lds[offB0[nf]];
      f16x8 bl = *(const f16x8*)&lds[8192 + offB0[nf]];
      MFMA4(af, bh, bl, acc, nf);
    }
    asm volatile("s_waitcnt lgkmcnt(0)\n\ts_barrier" ::: "memory");
  }

  const float sc_add = scal[0];
#pragma unroll
  for (int mf = 0; mf < 4; ++mf) {
#pragma unroll
    for (int r = 0; r < 4; ++r) {
      int row = m0 + ((w & 1) << 6) + (mf << 4) + (q << 2) + r;
      float radd = sc_add + rowAdd[(long long)bz * 256 + row];
#pragma unroll
      for (int nf = 0; nf < 4; ++nf) {
        int col = n0 + ((w >> 1) << 6) + (nf << 4) + l15;
        C[(long long)row * 256 + col] = acc[mf][nf][r] + radd;
      }
    }
  }
}

// ---------------------------------------------------------------------------
// tmpb[i] = dot(lefts[i,:], Wbil[0:H, H]) + Wbil[H,H].  One wave per row.
// ---------------------------------------------------------------------------
__global__ __launch_bounds__(64) void colvec_kernel(
    const float* __restrict__ lefts, const float* __restrict__ bcol,
    const float* __restrict__ corner, float* __restrict__ tmpb) {
  int row = blockIdx.x;
  int lane = threadIdx.x;
  const float* a = lefts + (long long)row * Hh;
  float s = 0.f;
#pragma unroll
  for (int h = lane; h < Hh; h += 64) s = fmaf(a[h], bcol[h], s);
#pragma unroll
  for (int off = 32; off > 0; off >>= 1) s += __shfl_down(s, off, 64);
  if (lane == 0) tmpb[row] = s + corner[0];
}

// ---------------------------------------------------------------------------
// CKY + backtrack. One block per batch, 1024 threads. Chart in LDS, packed
// triangular diag-major. EIGHT diagonals per barrier (see file header).
// ---------------------------------------------------------------------------
__global__ __launch_bounds__(1024) void cky_kernel(
    const float* __restrict__ scores,  // [64][256][256]
    uint8_t* __restrict__ Sws,         // [64][32896] packed triangular
    int* __restrict__ out)             // [2][64][256] int32
{
  const int b = blockIdx.x;
  const int t = threadIdx.x;
  const int n = Ss;
  const float* sc = scores + (long long)b * n * n;
  uint8_t* SP = Sws + (long long)b * 32896;

  __shared__ float Dch[32896];
  __shared__ float pv[2][2048];
  __shared__ uint8_t pmv[2][2048];
  __shared__ int stk[256];

  // offsets of tiny diags 0..15
  const int offT[16] = {0,    256,  511,  765,  1018, 1270, 1521, 1771,
                        2020, 2268, 2515, 2761, 3006, 3250, 3493, 3735};

  if (t < n) {
    out[b * n + t] = 0;
    out[Bb * n + b * n + t] = 0;
    Dch[t] = 0.f;  // diag 0
  }
  // s=2 reads pv[1]: its partial range is empty -> -inf sentinel
  pv[1][t] = -3.0e38f;
  pv[1][t + 1024] = -3.0e38f;

  // prologue score prefetch (diags 1..15 at cell t, clamped addresses)
  float PS[16];
  PS[0] = 0.f;
#pragma unroll
  for (int w = 1; w <= 15; ++w) {
    int ic = t;
    if (ic > 255 - w) ic = 255 - w;
    PS[w] = sc[ic * 257 + w];
  }
  asm volatile("s_waitcnt lgkmcnt(0)\n\ts_barrier" ::: "memory");

  // prologue: diags 1..15, one barrier each (generic ascending m-scan,
  // strict > = first-max)
#pragma unroll
  for (int w = 1; w <= 15; ++w) {
    if (t < 256 - w) {
      float bb = Dch[offT[w - 1] + t + 1];  // m=0: 0 + right
      int bm = 0;
#pragma unroll
      for (int m = 1; m < 15; ++m) {
        if (m >= w) break;
        float c = Dch[offT[m] + t] + Dch[offT[w - 1 - m] + t + m + 1];
        if (c > bb) { bb = c; bm = m; }
      }
      Dch[offT[w] + t] = PS[w] + bb;
      SP[offT[w] + t] = (uint8_t)bm;
    }
    asm volatile("s_waitcnt lgkmcnt(0)\n\ts_barrier" ::: "memory");
  }

  // (b): partials for superstep s+1 (8 diags, base W0b+8).
  // Covers m in [jb+8, W0b-1]; all spans are diags <= W0b-1 (>= 1 barrier
  // old when consumed). Slot = jb*256 + cell (RA) or jb*256+gb*128+cell.
  auto run_b = [&](int W0b, int pbuf) {
    const int cnv = n - W0b - 8;  // consumer's nv1
    int jb, gb, u, delta;
    if (cnv > 128) {  // RA: T=128, 1 group/diag, slices (u, u+128)
      jb = 7 - (t >> 7);
      gb = 0;
      u = t & 127;
      delta = 128;
    } else {  // RB/RC: T=64, 2 groups/diag
      const int wid = t >> 6;
      jb = 7 - (wid >> 1);
      gb = wid & 1;
      u = t & 63;
      delta = (cnv > 64) ? 64 : 0;
    }
    const int Wb = W0b + 8 + jb;
    const int nvb = n - Wb;
    int cnt = W0b - jb - 8;
    if (cnt < 0) cnt = 0;
    const int mlo = jb + 8;
    int ml, mh;
    if (cnv > 128) {
      ml = mlo;
      mh = mlo + cnt;
    } else {
      const int per = (cnt + 1) >> 1;
      ml = mlo + gb * per;
      mh = mlo + cnt;
      int e = ml + per;
      if (e < mh) mh = e;
    }
    float b0 = -3.0e38f, b1 = -3.0e38f;
    int m0i = ml, m1i = ml;
    if (u < nvb && ml < mh) {
      int al = ml * n - ((ml * (ml - 1)) >> 1) + u;
      const int kr = Wb - 1 - ml;
      int ar = kr * n - ((kr * (kr - 1)) >> 1) + u + ml + 1;
      int dl = n - ml;
      int dr = n - Wb + ml + 1;
      if (delta) {
#pragma unroll 4
        for (int m = ml; m < mh; ++m) {
          float l0 = Dch[al], l1 = Dch[al + delta];  // -> ds_read2_b32
          float r0 = Dch[ar], r1 = Dch[ar + delta];  // -> ds_read2_b32
          float c0 = l0 + r0, c1 = l1 + r1;
          if (c0 > b0) { b0 = c0; m0i = m; }  // strict > = first max
          if (c1 > b1) { b1 = c1; m1i = m; }
          al += dl;
          ar -= dr;
          --dl;
          ++dr;
        }
      } else {
#pragma unroll 8
        for (int m = ml; m < mh; ++m) {
          float c = Dch[al] + Dch[ar];
          if (c > b0) { b0 = c; m0i = m; }
          al += dl;
          ar -= dr;
          --dl;
          ++dr;
        }
      }
    }
    const int slot = jb * 256 + gb * 128 + u;
    pv[pbuf][slot] = b0;
    pmv[pbuf][slot] = (uint8_t)m0i;
    if (delta) {
      pv[pbuf][slot + delta] = b1;
      pmv[pbuf][slot + delta] = (uint8_t)m1i;
    }
  };

  // (a)-band geometry: wave wv covers cells 57*wv + lane (7-lane overlap)
  const int wv = t >> 6, lane = t & 63;
  const int tcell = 57 * wv + lane;

  // seed scores for s=2 (diags 16..23)
  float scA[8];
#pragma unroll
  for (int j = 0; j < 8; ++j) {
    const int Wn = 16 + j;
    int ic = tcell;
    if (ic > 255 - Wn) ic = 255 - Wn;
    scA[j] = sc[ic * 257 + Wn];
  }

  for (int s = 2; s <= 31; ++s) {
    const int W0 = 8 * s;
    const int nv1 = n - W0;
    const int pb = s & 1, po = pb ^ 1;
    const int nb = (nv1 + 56) / 57;

    // prefetch next superstep's scores (diags W0+8..W0+15)
    float P8[8] = {0.f, 0.f, 0.f, 0.f, 0.f, 0.f, 0.f, 0.f};
    if (s < 31 && wv < nb) {
#pragma unroll
      for (int j = 0; j < 8; ++j) {
        const int Wn = W0 + 8 + j;
        int ic = tcell;
        if (ic > 255 - Wn) ic = 255 - Wn;
        if (ic < 0) ic = 0;
        P8[j] = sc[ic * 257 + Wn];
      }
    }

    // ---- (a): finalize diags W0..W0+7 ----
    if (wv < nb) {
      const int tc = (tcell < nv1) ? tcell : (nv1 - 1);  // clamped (safe)
      const float* pvo = pv[po];
      const uint8_t* pmo = pmv[po];
      const bool RA = (nv1 > 128);
      int offPB[8], offCB[8];
#pragma unroll
      for (int d = 0; d < 8; ++d) {
        const int dg = W0 - 8 + d;
        offPB[d] = dg * 256 - ((dg * (dg - 1)) >> 1);
        const int cg = W0 + d;
        offCB[d] = cg * 256 - ((cg * (cg - 1)) >> 1);
      }
      float VAL[8];
#pragma unroll
      for (int j = 0; j < 8; ++j) {
        const int W = W0 + j;
        float bb;
        int bm = 0;
        // m = 0
        if (j == 0) {
          bb = Dch[offPB[7] + tc + 1];  // 0 + prev-batch diag W0-1
        } else {
          bb = __shfl_down(VAL[j - 1], 1, 64);  // 0 + VAL_{j-1}(c+1)
        }
        // dyn-low m in [1, j-1]
#pragma unroll
        for (int m = 1; m < 8; ++m) {
          if (m >= j) break;
          float c = Dch[offT[m] + tc] + __shfl_down(VAL[j - 1 - m], m + 1, 64);
          if (c > bb) { bb = c; bm = m; }
        }
        // static-low m in [max(j,1), j+7]
#pragma unroll
        for (int m2 = 0; m2 < 8; ++m2) {
          const int m = j + m2;
          if (m == 0) continue;  // handled as m=0
          float c = Dch[offT[m] + tc] + Dch[offPB[7 - m2] + tc + m + 1];
          if (c > bb) { bb = c; bm = m; }
        }
        // partials [j+8, W0-9]
        if (RA) {
          const int sl = j * 256 + tc;
          float x = pvo[sl];
          if (x > bb) { bb = x; bm = pmo[sl]; }
        } else {
#pragma unroll
          for (int g = 0; g < 2; ++g) {
            const int sl = j * 256 + g * 128 + tc;
            float x = pvo[sl];
            if (x > bb) { bb = x; bm = pmo[sl]; }
          }
        }
        // static-high m = W0-8+d, d = 0..7 (ascending)
#pragma unroll
        for (int d = 0; d < 8; ++d) {
          const int m = W0 - 8 + d;
          const int rp = j + 7 - d;  // right tiny diag
          float right = (rp == 0) ? 0.f : Dch[offT[rp] + tc + W - rp];
          float c = Dch[offPB[d] + tc] + right;
          if (c > bb) { bb = c; bm = m; }
        }
        // dyn-high m = W0+e, e in [0, j-1]
#pragma unroll
        for (int e = 0; e < 8; ++e) {
          if (e >= j) break;
          const int rp = j - 1 - e;
          float right = (rp == 0) ? 0.f : Dch[offT[rp] + tc + W - rp];
          float c = VAL[e] + right;
          if (c > bb) { bb = c; bm = W0 + e; }
        }
        VAL[j] = scA[j] + bb;
        if (lane <= 63 - j && tcell < nv1 - j) {
          Dch[offCB[j] + tcell] = VAL[j];
          SP[offCB[j] + tcell] = (uint8_t)bm;
        }
      }
    }

    // ---- (b): partials for superstep s+1 (diags W0+8..W0+15) ----
    if (s < 31) run_b(W0, pb);

    asm volatile("s_waitcnt lgkmcnt(0)\n\ts_barrier" ::: "memory");
#pragma unroll
    for (int j = 0; j < 8; ++j) scA[j] = P8[j];
  }

  // Drain all SP stores (whole loop's worth) once, then barrier.
  asm volatile("s_waitcnt vmcnt(0) lgkmcnt(0)\n\ts_barrier" ::: "memory");
  uint8_t* spl = (uint8_t*)Dch;
  for (int idx = t; idx < 32896; idx += 1024) spl[idx] = SP[idx];
  asm volatile("s_waitcnt vmcnt(0) lgkmcnt(0)\n\ts_barrier" ::: "memory");
  if (t == 0) {
    int top = 0;
    stk[top++] = (0 << 16) | (n - 1);
    int cnt = 0;
    for (int step = 0; step < n - 1; ++step) {
      if (top > 0) {
        int ij = stk[--top];
        int ii = ij >> 16, jj = ij & 0xffff;
        out[b * n + cnt] = ii;
        out[Bb * n + b * n + cnt] = jj;
        ++cnt;
        int k = jj - ii;
        int s2 = ii + (int)spl[k * n - ((k * (k - 1)) >> 1) + ii];
        stk[top] = (ii << 16) | s2;
        if (s2 > ii) ++top;
        stk[top] = ((s2 + 1) << 16) | jj;
        if (jj > s2 + 1) ++top;
      }
    }
  }
}

// ---------------------------------------------------------------------------
// Launch
// ---------------------------------------------------------------------------
extern "C" void kernel_launch(void* const* d_in, const int* in_sizes, int n_in,
                              void* d_out, int out_size, void* d_ws,
                              size_t ws_size, hipStream_t stream) {
  const float* X = (const float*)d_in[0];     // [64,256,1024]
  const float* Wl = (const float*)d_in[2];    // [1024,1024]
  const float* bl = (const float*)d_in[3];    // [1024]
  const float* Wr = (const float*)d_in[4];
  const float* br = (const float*)d_in[5];
  const float* Wbil = (const float*)d_in[6];  // [1025,1025]
  const float* bbil = (const float*)d_in[7];  // scalar
  int* out = (int*)d_out;

  // workspace layout
  float* ws = (float*)d_ws;
  float* lefts = ws;                          // 16777216 f
  float* rights = lefts + 16777216;           // 16777216 f
  float* tmpA = rights + 16777216;            // 16777216 f
  float* scoresP = tmpA + 16777216;           // 4194304 f
  float* tmpb = scoresP + 4194304;            // 16384 f
  float* browp = tmpb + 16384;                // 1024 f
  float* bcolp = browp + 1024;                // 1024 f
  float* cornerp = bcolp + 1024;              // 4 f
  unsigned short* Wlrt = (unsigned short*)(cornerp + 4);  // 2 x 2M fp16
  unsigned short* Wct = Wlrt + 2LL * 2097152;             // 2 x 1M fp16
  uint8_t* SPp = (uint8_t*)(Wct + 2LL * 1048576);         // 64x32896 u8

  // weight splits (+ Wbil bias vectors)
  splitw_kernel<<<dim3(4096), 256, 0, stream>>>(Wl, 1024, Wlrt, 2097152);
  splitw_kernel<<<dim3(4096), 256, 0, stream>>>(Wr, 1024, Wlrt + 1048576,
                                                2097152);
  splitw_kernel<<<dim3(4096), 256, 0, stream>>>(Wbil, 1025, Wct, 1048576);
  bilvec_kernel<<<dim3(4), 256, 0, stream>>>(Wbil, browp, bcolp, cornerp);

  // fused lefts|rights GEMM: N=2048
  dim3 gLR(16, 128);
  gemm_mfma_kernel<true><<<gLR, 256, 0, stream>>>(X, Wlrt, 2097152LL, lefts,
                                                  rights, bl, br);

  colvec_kernel<<<dim3(16384), 64, 0, stream>>>(lefts, bcolp, cornerp, tmpb);

  dim3 gA(8, 128);
  gemm_mfma_kernel<false><<<gA, 256, 0, stream>>>(lefts, Wct, 1048576LL, tmpA,
                                                  tmpA, browp, browp);

  dim3 g3(2, 2, 64);
  gemmnt_mfma_kernel<<<g3, 256, 0, stream>>>(tmpA, rights, scoresP, tmpb,
                                             bbil);

  cky_kernel<<<dim3(Bb), dim3(1024), 0, stream>>>(scoresP, SPp, out);
}